// Round 5
// baseline (646.896 us; speedup 1.0000x reference)
//
#include <hip/hip_runtime.h>
#include <stdint.h>
#include <math.h>

// (B,H,SQ,SK,D,DV) = (2,16,2048,2048,64,64)
// out = (softmax(q k^T) * 0.5) with dropout p=0.1 (jax threefry key 42, partitionable) @ v
// R5: k-split (32 waves/CU) + fixed-m softmax, tile body restructured in two
// sk-chunks to fit the 64-VGPR/8-wave budget (R4 spilled: WRITE_SIZE 285 MB).
namespace {
constexpr int Bb = 2, Hh = 16, SQc = 2048, SKc = 2048, Dc = 64, DVc = 64;
constexpr int TK = 64;

typedef __attribute__((ext_vector_type(8))) short short8;   // MFMA A/B frag (8 bf16)
typedef __attribute__((ext_vector_type(4))) float f32x4;    // MFMA C/D frag

__device__ __forceinline__ uint32_t rotl_(uint32_t x, int r) {
  return __builtin_amdgcn_alignbit(x, x, 32 - r);  // 1-instr rotate
}

// JAX threefry2x32, key=(0,42), partitionable: bits(i)=o0^o1 of threefry((0,42),(0,i)).
// keep iff bits < 0xE6666600 (exact integer form of uniform(bits) < 0.9f). VERIFIED R1-R4.
__device__ __forceinline__ uint32_t tf_bits(uint32_t ctr) {
  const uint32_t ks1 = 42u, ks2 = 0x1BD11BDAu ^ 42u;
  uint32_t x0 = 0u;
  uint32_t x1 = ctr + ks1;
#define TFR(r) { x0 += x1; x1 = rotl_(x1, r); x1 ^= x0; }
  TFR(13) TFR(15) TFR(26) TFR(6)
  x0 += ks1; x1 += ks2 + 1u;
  TFR(17) TFR(29) TFR(16) TFR(24)
  x0 += ks2; x1 += 0u + 2u;
  TFR(13) TFR(15) TFR(26) TFR(6)
  x0 += 0u; x1 += ks1 + 3u;
  TFR(17) TFR(29) TFR(16) TFR(24)
  x0 += ks1; x1 += ks2 + 4u;
  TFR(13) TFR(15) TFR(26) TFR(6)
  x0 += ks2; x1 += 0u + 5u;
#undef TFR
  return x0 ^ x1;
}

__device__ __forceinline__ uint32_t f2bf_u(float x) {  // RNE bf16 (finite x), low 16 bits
  uint32_t u = __float_as_uint(x);
  u += 0x7FFFu + ((u >> 16) & 1u);
  return u >> 16;
}
__device__ __forceinline__ uint32_t bfround(float x) {  // RNE bf16 in bits 31:16
  uint32_t u = __float_as_uint(x);
  return u + 0x7FFFu + ((u >> 16) & 1u);
}
}  // namespace

// Pre-pass: K -> Kh (bf16 hi) + Kl (bf16 residual), row-major [h][sk][d];
//           V -> Vt bf16 transposed [h][dv][sk].
__global__ __launch_bounds__(256) void prep_kernel(
    const float* __restrict__ k, const float* __restrict__ v,
    unsigned short* __restrict__ Khg, unsigned short* __restrict__ Klg,
    unsigned short* __restrict__ Vtg) {
  __shared__ float Vs[64 * 65];
  const int t = threadIdx.x;
  const int h = blockIdx.x >> 5;
  const int skt = blockIdx.x & 31;
  const size_t base = ((size_t)h * SKc + skt * 64) * Dc;
#pragma unroll
  for (int i = 0; i < 4; ++i) {
    int idx = t + 256 * i;
    int row = idx >> 4, d0 = (idx & 15) << 2;
    float4 kv = *(const float4*)(k + base + row * Dc + d0);
    uint32_t hx = f2bf_u(kv.x), hy = f2bf_u(kv.y), hz = f2bf_u(kv.z), hw = f2bf_u(kv.w);
    uint32_t lx = f2bf_u(kv.x - __uint_as_float(hx << 16));
    uint32_t ly = f2bf_u(kv.y - __uint_as_float(hy << 16));
    uint32_t lz = f2bf_u(kv.z - __uint_as_float(hz << 16));
    uint32_t lw = f2bf_u(kv.w - __uint_as_float(hw << 16));
    *(ushort4*)(Khg + base + row * Dc + d0) =
        make_ushort4((unsigned short)hx, (unsigned short)hy, (unsigned short)hz, (unsigned short)hw);
    *(ushort4*)(Klg + base + row * Dc + d0) =
        make_ushort4((unsigned short)lx, (unsigned short)ly, (unsigned short)lz, (unsigned short)lw);
    float4 vv = *(const float4*)(v + base + row * Dc + d0);  // DVc == Dc
    *(float4*)(&Vs[row * 65 + d0]) = vv;
  }
  __syncthreads();
  const int dv = t >> 2, sk0 = (t & 3) << 4;
  unsigned short tmp[16];
#pragma unroll
  for (int j = 0; j < 16; ++j) tmp[j] = (unsigned short)f2bf_u(Vs[(sk0 + j) * 65 + dv]);
  unsigned short* vp = Vtg + ((size_t)h * DVc + dv) * SKc + skt * 64 + sk0;
  *(short8*)(vp) = *(const short8*)&tmp[0];
  *(short8*)(vp + 8) = *(const short8*)&tmp[8];
}

__global__ __launch_bounds__(256, 8) void attn_main(
    const float* __restrict__ q, const unsigned short* __restrict__ Khg,
    const unsigned short* __restrict__ Klg, const unsigned short* __restrict__ Vtg,
    float* __restrict__ out) {
  const int t = threadIdx.x;
  const int lane = t & 63;
  const int w = t >> 6;
  const int lm = lane & 15;
  const int quad = lane >> 4;
  const int qsub = w >> 1;   // which 16-q-row group (block covers 32 q rows)
  const int khalf = w & 1;   // which half of the 2048 keys

  // XCD swizzle: 256 consecutive vids (4 heads) per XCD -> K/V L2-resident
  const int vid = (blockIdx.x & 7) * 256 + (blockIdx.x >> 3);
  const int qt = vid & 63;
  const int h = (vid >> 6) & 15;
  const int b = vid >> 10;
  const int qrow = qt * 32 + qsub * 16 + lm;

  // ---- Q B-frags (fp32 -> split bf16 in regs), constant over k-loop ----
  short8 qh[2], ql[2];
  {
    const float* qp = q + (((size_t)(b * Hh + h)) * SQc + qrow) * Dc;
#pragma unroll
    for (int c = 0; c < 2; ++c) {
#pragma unroll
      for (int j2 = 0; j2 < 2; ++j2) {
        float4 x = *(const float4*)(qp + c * 32 + quad * 8 + j2 * 4);
        float xs[4] = {x.x, x.y, x.z, x.w};
#pragma unroll
        for (int j = 0; j < 4; ++j) {
          uint32_t hb = f2bf_u(xs[j]);
          float lo = xs[j] - __uint_as_float(hb << 16);
          qh[c][j2 * 4 + j] = (short)hb;
          ql[c][j2 * 4 + j] = (short)f2bf_u(lo);
        }
      }
    }
  }

  const unsigned short* kh_base = Khg + (size_t)h * SKc * Dc;
  const unsigned short* kl_base = Klg + (size_t)h * SKc * Dc;
  const unsigned short* vt_base = Vtg + (size_t)h * DVc * SKc;

  f32x4 acc[4] = {{0.f, 0.f, 0.f, 0.f}, {0.f, 0.f, 0.f, 0.f},
                  {0.f, 0.f, 0.f, 0.f}, {0.f, 0.f, 0.f, 0.f}};
  float l_i = 0.f;  // per-lane partial denominator (fixed m=0), reduced at the end

  // bpermute byte-addresses for the cross-quad P exchange (constant per lane)
  const int a0 = ((quad & 1) * 32 + lm) << 2;
  const int a1 = a0 + 64;
  const uint32_t sel = (quad >= 2) ? 0x07060302u : 0x05040100u;

  uint32_t ctile = ((uint32_t)((b * Hh + h) * SQc + qrow)) * (uint32_t)SKc +
                   (uint32_t)(khalf * 16 * TK + quad * 4);

  const int kt0 = khalf * 16;
  for (int kt = kt0; kt < kt0 + 16; ++kt, ctile += TK) {
    // lane-invariant-per-tile K base for this tile (rows kt*64 + .. + lm)
    const unsigned short* khp = kh_base + (size_t)(kt * TK + lm) * Dc + quad * 8;
    const unsigned short* klp = kl_base + (size_t)(kt * TK + lm) * Dc + quad * 8;

#pragma unroll
    for (int c = 0; c < 2; ++c) {
      // ---- S^T for nb = 2c, 2c+1 (rows (2c)*16, (2c+1)*16): 3-term split ----
      f32x4 s0 = {0.f, 0.f, 0.f, 0.f}, s1 = {0.f, 0.f, 0.f, 0.f};
#pragma unroll
      for (int d = 0; d < 2; ++d) {
        short8 kh0 = *(const short8*)(khp + (2 * c) * 16 * Dc + d * 32);
        short8 kl0 = *(const short8*)(klp + (2 * c) * 16 * Dc + d * 32);
        s0 = __builtin_amdgcn_mfma_f32_16x16x32_bf16(kh0, qh[d], s0, 0, 0, 0);
        s0 = __builtin_amdgcn_mfma_f32_16x16x32_bf16(kl0, qh[d], s0, 0, 0, 0);
        s0 = __builtin_amdgcn_mfma_f32_16x16x32_bf16(kh0, ql[d], s0, 0, 0, 0);
        short8 kh1 = *(const short8*)(khp + (2 * c + 1) * 16 * Dc + d * 32);
        short8 kl1 = *(const short8*)(klp + (2 * c + 1) * 16 * Dc + d * 32);
        s1 = __builtin_amdgcn_mfma_f32_16x16x32_bf16(kh1, qh[d], s1, 0, 0, 0);
        s1 = __builtin_amdgcn_mfma_f32_16x16x32_bf16(kl1, qh[d], s1, 0, 0, 0);
        s1 = __builtin_amdgcn_mfma_f32_16x16x32_bf16(kh1, ql[d], s1, 0, 0, 0);
      }

      // ---- p = e^s (fixed m: |s|<~50, fp32-safe); dropout; pack bf16 pairs ----
      uint32_t pkc[4];
#pragma unroll
      for (int r = 0; r < 4; ++r) {
        float p0 = __expf(s0[r]);
        float p1 = __expf(s1[r]);
        l_i += p0 + p1;  // denominator over UNdropped probs
        uint32_t b0 = tf_bits(ctile + (uint32_t)(c * 32 + r));
        uint32_t b1 = tf_bits(ctile + (uint32_t)(c * 32 + 16 + r));
        uint32_t u0 = (b0 < 0xE6666600u) ? bfround(p0) : 0u;
        uint32_t u1 = (b1 < 0xE6666600u) ? bfround(p1) : 0u;
        pkc[r] = __builtin_amdgcn_perm(u1, u0, 0x07060302u);  // (bf(p1)<<16)|bf(p0)
      }

      // ---- P^T B-frag for this sk-chunk via cross-quad bpermute ----
      short8 pb;
      {
        uint32_t e0 = (uint32_t)__builtin_amdgcn_ds_bpermute(a0, (int)pkc[0]);
        uint32_t e1 = (uint32_t)__builtin_amdgcn_ds_bpermute(a0, (int)pkc[1]);
        uint32_t e2 = (uint32_t)__builtin_amdgcn_ds_bpermute(a0, (int)pkc[2]);
        uint32_t e3 = (uint32_t)__builtin_amdgcn_ds_bpermute(a0, (int)pkc[3]);
        uint32_t f0 = (uint32_t)__builtin_amdgcn_ds_bpermute(a1, (int)pkc[0]);
        uint32_t f1 = (uint32_t)__builtin_amdgcn_ds_bpermute(a1, (int)pkc[1]);
        uint32_t f2 = (uint32_t)__builtin_amdgcn_ds_bpermute(a1, (int)pkc[2]);
        uint32_t f3 = (uint32_t)__builtin_amdgcn_ds_bpermute(a1, (int)pkc[3]);
        uint32_t w0 = __builtin_amdgcn_perm(e1, e0, sel);
        uint32_t w1 = __builtin_amdgcn_perm(e3, e2, sel);
        uint32_t w2 = __builtin_amdgcn_perm(f1, f0, sel);
        uint32_t w3 = __builtin_amdgcn_perm(f3, f2, sel);
        uint32_t tmp[4] = {w0, w1, w2, w3};
        pb = *(const short8*)tmp;  // B[k=quad*8+j][n=lm] for sk-chunk c
      }

      // ---- O^T += V^T(chunk c) . P^T(chunk c) ----
#pragma unroll
      for (int nb = 0; nb < 4; ++nb) {
        const unsigned short* vr =
            vt_base + (size_t)(nb * 16 + lm) * SKc + kt * TK + c * 32 + quad * 8;
        short8 vb = *(const short8*)vr;
        acc[nb] = __builtin_amdgcn_mfma_f32_16x16x32_bf16(vb, pb, acc[nb], 0, 0, 0);
      }
    }
  }

  // ---- reduce l across quads (once) ----
  l_i += __shfl_xor(l_i, 16);
  l_i += __shfl_xor(l_i, 32);

  // ---- combine the two k-halves via LDS (fixed m -> partials are summable) ----
  __shared__ float Lacc[2][16][72];  // [qsub][q=lm][dv], stride 72 floats
  __shared__ float Ll[2][16];
  if (khalf == 1) {
#pragma unroll
    for (int nb = 0; nb < 4; ++nb)
      *(f32x4*)&Lacc[qsub][lm][nb * 16 + quad * 4] = acc[nb];
    if (quad == 0) Ll[qsub][lm] = l_i;
  }
  __syncthreads();
  if (khalf == 0) {
    float lt = l_i + Ll[qsub][lm];
    float sc = (0.5f / 0.9f) / lt;
    float* op = out + (((size_t)(b * Hh + h)) * SQc + qrow) * DVc;
#pragma unroll
    for (int nb = 0; nb < 4; ++nb) {
      f32x4 other = *(const f32x4*)&Lacc[qsub][lm][nb * 16 + quad * 4];
      float4 o = make_float4((acc[nb][0] + other[0]) * sc, (acc[nb][1] + other[1]) * sc,
                             (acc[nb][2] + other[2]) * sc, (acc[nb][3] + other[3]) * sc);
      *(float4*)(op + nb * 16 + quad * 4) = o;
    }
  }
}

extern "C" void kernel_launch(void* const* d_in, const int* in_sizes, int n_in,
                              void* d_out, int out_size, void* d_ws, size_t ws_size,
                              hipStream_t stream) {
  const float* q = (const float*)d_in[0];
  const float* k = (const float*)d_in[1];
  const float* v = (const float*)d_in[2];
  float* out = (float*)d_out;
  // ws layout: Kh (4 MB) | Kl (4 MB) | Vt (4 MB)
  unsigned short* Khg = (unsigned short*)d_ws;
  unsigned short* Klg = Khg + (size_t)Hh * SKc * Dc;
  unsigned short* Vtg = Klg + (size_t)Hh * SKc * Dc;
  prep_kernel<<<dim3(Hh * 32), 256, 0, stream>>>(k, v, Khg, Klg, Vtg);
  attn_main<<<dim3(Bb * Hh * (SQc / 32)), 256, 0, stream>>>(q, Khg, Klg, Vtg, out);
}

// Round 6
// 458.433 us; speedup vs baseline: 1.4111x; 1.4111x over previous
//
#include <hip/hip_runtime.h>
#include <stdint.h>
#include <math.h>

// (B,H,SQ,SK,D,DV) = (2,16,2048,2048,64,64)
// out = (softmax(q k^T) * 0.5) with dropout p=0.1 (jax threefry key 42, partitionable) @ v
// R6: R5 body (k-split, fixed-m softmax, chunked tile) with __launch_bounds__(256,6):
// 85-reg budget kills the spill (R4/R5 at (256,8)=64 regs spilled 285/932 MB).
namespace {
constexpr int Bb = 2, Hh = 16, SQc = 2048, SKc = 2048, Dc = 64, DVc = 64;
constexpr int TK = 64;

typedef __attribute__((ext_vector_type(8))) short short8;   // MFMA A/B frag (8 bf16)
typedef __attribute__((ext_vector_type(4))) float f32x4;    // MFMA C/D frag

__device__ __forceinline__ uint32_t rotl_(uint32_t x, int r) {
  return __builtin_amdgcn_alignbit(x, x, 32 - r);  // 1-instr rotate
}

// JAX threefry2x32, key=(0,42), partitionable: bits(i)=o0^o1 of threefry((0,42),(0,i)).
// keep iff bits < 0xE6666600 (exact integer form of uniform(bits) < 0.9f). VERIFIED R1-R5.
__device__ __forceinline__ uint32_t tf_bits(uint32_t ctr) {
  const uint32_t ks1 = 42u, ks2 = 0x1BD11BDAu ^ 42u;
  uint32_t x0 = 0u;
  uint32_t x1 = ctr + ks1;
#define TFR(r) { x0 += x1; x1 = rotl_(x1, r); x1 ^= x0; }
  TFR(13) TFR(15) TFR(26) TFR(6)
  x0 += ks1; x1 += ks2 + 1u;
  TFR(17) TFR(29) TFR(16) TFR(24)
  x0 += ks2; x1 += 0u + 2u;
  TFR(13) TFR(15) TFR(26) TFR(6)
  x0 += 0u; x1 += ks1 + 3u;
  TFR(17) TFR(29) TFR(16) TFR(24)
  x0 += ks1; x1 += ks2 + 4u;
  TFR(13) TFR(15) TFR(26) TFR(6)
  x0 += ks2; x1 += 0u + 5u;
#undef TFR
  return x0 ^ x1;
}

__device__ __forceinline__ uint32_t f2bf_u(float x) {  // RNE bf16 (finite x), low 16 bits
  uint32_t u = __float_as_uint(x);
  u += 0x7FFFu + ((u >> 16) & 1u);
  return u >> 16;
}
__device__ __forceinline__ uint32_t bfround(float x) {  // RNE bf16 in bits 31:16
  uint32_t u = __float_as_uint(x);
  return u + 0x7FFFu + ((u >> 16) & 1u);
}
}  // namespace

// Pre-pass: K -> Kh (bf16 hi) + Kl (bf16 residual), row-major [h][sk][d];
//           V -> Vt bf16 transposed [h][dv][sk].
__global__ __launch_bounds__(256) void prep_kernel(
    const float* __restrict__ k, const float* __restrict__ v,
    unsigned short* __restrict__ Khg, unsigned short* __restrict__ Klg,
    unsigned short* __restrict__ Vtg) {
  __shared__ float Vs[64 * 65];
  const int t = threadIdx.x;
  const int h = blockIdx.x >> 5;
  const int skt = blockIdx.x & 31;
  const size_t base = ((size_t)h * SKc + skt * 64) * Dc;
#pragma unroll
  for (int i = 0; i < 4; ++i) {
    int idx = t + 256 * i;
    int row = idx >> 4, d0 = (idx & 15) << 2;
    float4 kv = *(const float4*)(k + base + row * Dc + d0);
    uint32_t hx = f2bf_u(kv.x), hy = f2bf_u(kv.y), hz = f2bf_u(kv.z), hw = f2bf_u(kv.w);
    uint32_t lx = f2bf_u(kv.x - __uint_as_float(hx << 16));
    uint32_t ly = f2bf_u(kv.y - __uint_as_float(hy << 16));
    uint32_t lz = f2bf_u(kv.z - __uint_as_float(hz << 16));
    uint32_t lw = f2bf_u(kv.w - __uint_as_float(hw << 16));
    *(ushort4*)(Khg + base + row * Dc + d0) =
        make_ushort4((unsigned short)hx, (unsigned short)hy, (unsigned short)hz, (unsigned short)hw);
    *(ushort4*)(Klg + base + row * Dc + d0) =
        make_ushort4((unsigned short)lx, (unsigned short)ly, (unsigned short)lz, (unsigned short)lw);
    float4 vv = *(const float4*)(v + base + row * Dc + d0);  // DVc == Dc
    *(float4*)(&Vs[row * 65 + d0]) = vv;
  }
  __syncthreads();
  const int dv = t >> 2, sk0 = (t & 3) << 4;
  unsigned short tmp[16];
#pragma unroll
  for (int j = 0; j < 16; ++j) tmp[j] = (unsigned short)f2bf_u(Vs[(sk0 + j) * 65 + dv]);
  unsigned short* vp = Vtg + ((size_t)h * DVc + dv) * SKc + skt * 64 + sk0;
  *(short8*)(vp) = *(const short8*)&tmp[0];
  *(short8*)(vp + 8) = *(const short8*)&tmp[8];
}

__global__ __launch_bounds__(256, 6) void attn_main(
    const float* __restrict__ q, const unsigned short* __restrict__ Khg,
    const unsigned short* __restrict__ Klg, const unsigned short* __restrict__ Vtg,
    float* __restrict__ out) {
  const int t = threadIdx.x;
  const int lane = t & 63;
  const int w = t >> 6;
  const int lm = lane & 15;
  const int quad = lane >> 4;
  const int qsub = w >> 1;   // which 16-q-row group (block covers 32 q rows)
  const int khalf = w & 1;   // which half of the 2048 keys

  // XCD swizzle: 256 consecutive vids (4 heads) per XCD -> K/V L2-resident
  const int vid = (blockIdx.x & 7) * 256 + (blockIdx.x >> 3);
  const int qt = vid & 63;
  const int h = (vid >> 6) & 15;
  const int b = vid >> 10;
  const int qrow = qt * 32 + qsub * 16 + lm;

  // ---- Q B-frags (fp32 -> split bf16 in regs), constant over k-loop ----
  short8 qh[2], ql[2];
  {
    const float* qp = q + (((size_t)(b * Hh + h)) * SQc + qrow) * Dc;
#pragma unroll
    for (int c = 0; c < 2; ++c) {
#pragma unroll
      for (int j2 = 0; j2 < 2; ++j2) {
        float4 x = *(const float4*)(qp + c * 32 + quad * 8 + j2 * 4);
        float xs[4] = {x.x, x.y, x.z, x.w};
#pragma unroll
        for (int j = 0; j < 4; ++j) {
          uint32_t hb = f2bf_u(xs[j]);
          float lo = xs[j] - __uint_as_float(hb << 16);
          qh[c][j2 * 4 + j] = (short)hb;
          ql[c][j2 * 4 + j] = (short)f2bf_u(lo);
        }
      }
    }
  }

  const unsigned short* kh_base = Khg + (size_t)h * SKc * Dc;
  const unsigned short* kl_base = Klg + (size_t)h * SKc * Dc;
  const unsigned short* vt_base = Vtg + (size_t)h * DVc * SKc;

  f32x4 acc[4] = {{0.f, 0.f, 0.f, 0.f}, {0.f, 0.f, 0.f, 0.f},
                  {0.f, 0.f, 0.f, 0.f}, {0.f, 0.f, 0.f, 0.f}};
  float l_i = 0.f;  // per-lane partial denominator (fixed m=0), reduced at the end

  // bpermute byte-addresses for the cross-quad P exchange (constant per lane)
  const int a0 = ((quad & 1) * 32 + lm) << 2;
  const int a1 = a0 + 64;
  const uint32_t sel = (quad >= 2) ? 0x07060302u : 0x05040100u;

  uint32_t ctile = ((uint32_t)((b * Hh + h) * SQc + qrow)) * (uint32_t)SKc +
                   (uint32_t)(khalf * 16 * TK + quad * 4);

  const int kt0 = khalf * 16;
  for (int kt = kt0; kt < kt0 + 16; ++kt, ctile += TK) {
    // lane-invariant-per-tile K base for this tile (rows kt*64 + .. + lm)
    const unsigned short* khp = kh_base + (size_t)(kt * TK + lm) * Dc + quad * 8;
    const unsigned short* klp = kl_base + (size_t)(kt * TK + lm) * Dc + quad * 8;

#pragma unroll
    for (int c = 0; c < 2; ++c) {
      // ---- S^T for nb = 2c, 2c+1 (rows (2c)*16, (2c+1)*16): 3-term split ----
      f32x4 s0 = {0.f, 0.f, 0.f, 0.f}, s1 = {0.f, 0.f, 0.f, 0.f};
#pragma unroll
      for (int d = 0; d < 2; ++d) {
        short8 kh0 = *(const short8*)(khp + (2 * c) * 16 * Dc + d * 32);
        short8 kl0 = *(const short8*)(klp + (2 * c) * 16 * Dc + d * 32);
        s0 = __builtin_amdgcn_mfma_f32_16x16x32_bf16(kh0, qh[d], s0, 0, 0, 0);
        s0 = __builtin_amdgcn_mfma_f32_16x16x32_bf16(kl0, qh[d], s0, 0, 0, 0);
        s0 = __builtin_amdgcn_mfma_f32_16x16x32_bf16(kh0, ql[d], s0, 0, 0, 0);
        short8 kh1 = *(const short8*)(khp + (2 * c + 1) * 16 * Dc + d * 32);
        short8 kl1 = *(const short8*)(klp + (2 * c + 1) * 16 * Dc + d * 32);
        s1 = __builtin_amdgcn_mfma_f32_16x16x32_bf16(kh1, qh[d], s1, 0, 0, 0);
        s1 = __builtin_amdgcn_mfma_f32_16x16x32_bf16(kl1, qh[d], s1, 0, 0, 0);
        s1 = __builtin_amdgcn_mfma_f32_16x16x32_bf16(kh1, ql[d], s1, 0, 0, 0);
      }

      // ---- p = e^s (fixed m: |s|<~50, fp32-safe); dropout; pack bf16 pairs ----
      uint32_t pkc[4];
#pragma unroll
      for (int r = 0; r < 4; ++r) {
        float p0 = __expf(s0[r]);
        float p1 = __expf(s1[r]);
        l_i += p0 + p1;  // denominator over UNdropped probs
        uint32_t b0 = tf_bits(ctile + (uint32_t)(c * 32 + r));
        uint32_t b1 = tf_bits(ctile + (uint32_t)(c * 32 + 16 + r));
        uint32_t u0 = (b0 < 0xE6666600u) ? bfround(p0) : 0u;
        uint32_t u1 = (b1 < 0xE6666600u) ? bfround(p1) : 0u;
        pkc[r] = __builtin_amdgcn_perm(u1, u0, 0x07060302u);  // (bf(p1)<<16)|bf(p0)
      }

      // ---- P^T B-frag for this sk-chunk via cross-quad bpermute ----
      short8 pb;
      {
        uint32_t e0 = (uint32_t)__builtin_amdgcn_ds_bpermute(a0, (int)pkc[0]);
        uint32_t e1 = (uint32_t)__builtin_amdgcn_ds_bpermute(a0, (int)pkc[1]);
        uint32_t e2 = (uint32_t)__builtin_amdgcn_ds_bpermute(a0, (int)pkc[2]);
        uint32_t e3 = (uint32_t)__builtin_amdgcn_ds_bpermute(a0, (int)pkc[3]);
        uint32_t f0 = (uint32_t)__builtin_amdgcn_ds_bpermute(a1, (int)pkc[0]);
        uint32_t f1 = (uint32_t)__builtin_amdgcn_ds_bpermute(a1, (int)pkc[1]);
        uint32_t f2 = (uint32_t)__builtin_amdgcn_ds_bpermute(a1, (int)pkc[2]);
        uint32_t f3 = (uint32_t)__builtin_amdgcn_ds_bpermute(a1, (int)pkc[3]);
        uint32_t w0 = __builtin_amdgcn_perm(e1, e0, sel);
        uint32_t w1 = __builtin_amdgcn_perm(e3, e2, sel);
        uint32_t w2 = __builtin_amdgcn_perm(f1, f0, sel);
        uint32_t w3 = __builtin_amdgcn_perm(f3, f2, sel);
        uint32_t tmp[4] = {w0, w1, w2, w3};
        pb = *(const short8*)tmp;  // B[k=quad*8+j][n=lm] for sk-chunk c
      }

      // ---- O^T += V^T(chunk c) . P^T(chunk c) ----
#pragma unroll
      for (int nb = 0; nb < 4; ++nb) {
        const unsigned short* vr =
            vt_base + (size_t)(nb * 16 + lm) * SKc + kt * TK + c * 32 + quad * 8;
        short8 vb = *(const short8*)vr;
        acc[nb] = __builtin_amdgcn_mfma_f32_16x16x32_bf16(vb, pb, acc[nb], 0, 0, 0);
      }
    }
  }

  // ---- reduce l across quads (once) ----
  l_i += __shfl_xor(l_i, 16);
  l_i += __shfl_xor(l_i, 32);

  // ---- combine the two k-halves via LDS (fixed m -> partials are summable) ----
  __shared__ float Lacc[2][16][72];  // [qsub][q=lm][dv], stride 72 floats
  __shared__ float Ll[2][16];
  if (khalf == 1) {
#pragma unroll
    for (int nb = 0; nb < 4; ++nb)
      *(f32x4*)&Lacc[qsub][lm][nb * 16 + quad * 4] = acc[nb];
    if (quad == 0) Ll[qsub][lm] = l_i;
  }
  __syncthreads();
  if (khalf == 0) {
    float lt = l_i + Ll[qsub][lm];
    float sc = (0.5f / 0.9f) / lt;
    float* op = out + (((size_t)(b * Hh + h)) * SQc + qrow) * DVc;
#pragma unroll
    for (int nb = 0; nb < 4; ++nb) {
      f32x4 other = *(const f32x4*)&Lacc[qsub][lm][nb * 16 + quad * 4];
      float4 o = make_float4((acc[nb][0] + other[0]) * sc, (acc[nb][1] + other[1]) * sc,
                             (acc[nb][2] + other[2]) * sc, (acc[nb][3] + other[3]) * sc);
      *(float4*)(op + nb * 16 + quad * 4) = o;
    }
  }
}

extern "C" void kernel_launch(void* const* d_in, const int* in_sizes, int n_in,
                              void* d_out, int out_size, void* d_ws, size_t ws_size,
                              hipStream_t stream) {
  const float* q = (const float*)d_in[0];
  const float* k = (const float*)d_in[1];
  const float* v = (const float*)d_in[2];
  float* out = (float*)d_out;
  // ws layout: Kh (4 MB) | Kl (4 MB) | Vt (4 MB)
  unsigned short* Khg = (unsigned short*)d_ws;
  unsigned short* Klg = Khg + (size_t)Hh * SKc * Dc;
  unsigned short* Vtg = Klg + (size_t)Hh * SKc * Dc;
  prep_kernel<<<dim3(Hh * 32), 256, 0, stream>>>(k, v, Khg, Klg, Vtg);
  attn_main<<<dim3(Bb * Hh * (SQc / 32)), 256, 0, stream>>>(q, Khg, Klg, Vtg, out);
}